// Round 1
// baseline (496.482 us; speedup 1.0000x reference)
//
#include <hip/hip_runtime.h>

// VQ-VAE VectorQuantizer forward, MI355X (gfx950)
// inputs: d_in[0] = x (64*32*32*64 f32 = 65536 x 64), d_in[1] = w (1024 x 64 f32)
// out (f32, flat): [0 .. 4194304)   quantized_st (== w[idx] numerically)
//                  [4194304]        loss = 0.25 * mean((q - x)^2)
//                  [4194305 .. +65536) encodings_indices (written as float)
//                  [4259841 .. +65536) w.T  (wt[d*1024 + k] = w[k*64 + d])

#define N_VEC 65536
#define D 64
#define K 1024
#define BETA 0.25f

#define OFF_Q    0
#define OFF_LOSS 4194304
#define OFF_IDX  4194305
#define OFF_WT   4259841

__global__ __launch_bounds__(256) void vq_prep(const float* __restrict__ w,
                                               float* __restrict__ halfwsq,
                                               float* __restrict__ out_wt) {
  int t = blockIdx.x * 256 + threadIdx.x;   // 0..65535, t = d*1024 + k (coalesced wt write)
  int k = t & (K - 1);
  int d = t >> 10;
  out_wt[t] = w[(size_t)k * D + d];
  if (t < K) {
    const float4* wr = (const float4*)(w + (size_t)t * D);
    float s = 0.f;
#pragma unroll
    for (int i = 0; i < 16; ++i) {
      float4 v = wr[i];
      s += v.x * v.x + v.y * v.y + v.z * v.z + v.w * v.w;
    }
    halfwsq[t] = 0.5f * s;
  }
}

__global__ __launch_bounds__(256) void vq_main(const float* __restrict__ x,
                                               const float* __restrict__ w,
                                               const float* __restrict__ halfwsq,
                                               float* __restrict__ out) {
  int n = blockIdx.x * 256 + threadIdx.x;   // one vector per thread; grid covers N exactly
  const float4* xp = (const float4*)(x + (size_t)n * D);
  float4 xv[16];
#pragma unroll
  for (int i = 0; i < 16; ++i) xv[i] = xp[i];

  // argmax_k ( x . w_k - 0.5*||w_k||^2 )  ==  argmin_k ||x - w_k||^2
  // strict > keeps the FIRST maximal index (matches jnp.argmax tie-break).
  float best = -1e30f;
  int bidx = 0;
  for (int k = 0; k < K; ++k) {
    // k is wave-uniform -> w row address is uniform -> scalar loads expected
    const float4* wr = (const float4*)(w + (size_t)k * D);
    float hw = halfwsq[k];
    float4 a;
    a.x = -hw; a.y = 0.f; a.z = 0.f; a.w = 0.f;
#pragma unroll
    for (int i = 0; i < 16; ++i) {
      float4 wv = wr[i];
      a.x = fmaf(xv[i].x, wv.x, a.x);
      a.y = fmaf(xv[i].y, wv.y, a.y);
      a.z = fmaf(xv[i].z, wv.z, a.z);
      a.w = fmaf(xv[i].w, wv.w, a.w);
    }
    float m = (a.x + a.y) + (a.z + a.w);
    if (m > best) { best = m; bidx = k; }
  }

  // epilogue: gather chosen codeword, write quantized + index, accumulate loss
  const float4* qr = (const float4*)(w + (size_t)bidx * D);
  float4* oq = (float4*)(out + OFF_Q + (size_t)n * D);
  float sse = 0.f;
#pragma unroll
  for (int i = 0; i < 16; ++i) {
    float4 q = qr[i];
    oq[i] = q;
    float d0 = xv[i].x - q.x, d1 = xv[i].y - q.y;
    float d2 = xv[i].z - q.z, d3 = xv[i].w - q.w;
    sse += d0 * d0 + d1 * d1 + d2 * d2 + d3 * d3;
  }
  out[OFF_IDX + n] = (float)bidx;

  // wave-level reduction (wave64), one atomic per wave
#pragma unroll
  for (int off = 32; off >= 1; off >>= 1)
    sse += __shfl_xor(sse, off, 64);
  if ((threadIdx.x & 63) == 0)
    atomicAdd(out + OFF_LOSS, sse * (BETA / (float)(N_VEC * D)));
}

extern "C" void kernel_launch(void* const* d_in, const int* in_sizes, int n_in,
                              void* d_out, int out_size, void* d_ws, size_t ws_size,
                              hipStream_t stream) {
  const float* x = (const float*)d_in[0];
  const float* w = (const float*)d_in[1];
  float* out = (float*)d_out;
  float* halfwsq = (float*)d_ws;   // 1024 floats of scratch

  // zero the loss accumulator (d_out is re-poisoned before every timed launch)
  hipMemsetAsync(out + OFF_LOSS, 0, sizeof(float), stream);
  vq_prep<<<256, 256, 0, stream>>>(w, halfwsq, out + OFF_WT);
  vq_main<<<256, 256, 0, stream>>>(x, w, halfwsq, out);
}

// Round 2
// 287.524 us; speedup vs baseline: 1.7267x; 1.7267x over previous
//
#include <hip/hip_runtime.h>

// VQ-VAE VectorQuantizer forward, MI355X (gfx950)
// inputs: d_in[0] = x (65536 x 64 f32), d_in[1] = w (1024 x 64 f32)
// out (f32 flat): [0..4194304) quantized, [4194304] loss,
//                 [4194305..+65536) indices (as float), [4259841..+65536) w.T

#define N_VEC 65536
#define D 64
#define K 1024
#define BETA 0.25f

#define OFF_Q    0
#define OFF_LOSS 4194304
#define OFF_IDX  4194305
#define OFF_WT   4259841

#define TPB    1024          // threads per block (16 waves -> 4 waves/SIMD)
#define VPB    256           // vectors per block
#define GROUPS 4             // k-split groups
#define CK     128           // codewords staged per chunk (32 KB)
#define NCHUNK (K / CK)      // 8
#define CKG    (CK / GROUPS) // 32 codewords per group per chunk

typedef __attribute__((address_space(3))) void lds_void_t;
typedef __attribute__((address_space(1))) const void gbl_void_t;

__global__ __launch_bounds__(256) void vq_prep(const float* __restrict__ w,
                                               float* __restrict__ halfwsq,
                                               float* __restrict__ out_wt) {
  int t = blockIdx.x * 256 + threadIdx.x;   // t = d*1024 + k (coalesced wt write)
  int k = t & (K - 1);
  int d = t >> 10;
  out_wt[t] = w[(size_t)k * D + d];
  if (t < K) {
    const float4* wr = (const float4*)(w + (size_t)t * D);
    float s = 0.f;
#pragma unroll
    for (int i = 0; i < 16; ++i) {
      float4 v = wr[i];
      s += v.x * v.x + v.y * v.y + v.z * v.z + v.w * v.w;
    }
    halfwsq[t] = 0.5f * s;
  }
}

__global__ __launch_bounds__(TPB) void vq_main(const float* __restrict__ x,
                                               const float* __restrict__ w,
                                               const float* __restrict__ hq,
                                               float* __restrict__ out) {
  __shared__ float s_w[2][CK * D];       // 2 x 32 KB staged codewords
  __shared__ float s_h[2][CK];           // 2 x 512 B staged 0.5*||w||^2
  __shared__ float s_ms[GROUPS * VPB];   // merge scores
  __shared__ int   s_mi[GROUPS * VPB];   // merge indices

  const int vid = threadIdx.x & (VPB - 1);   // vector within block
  const int grp = threadIdx.x >> 8;          // k-split group 0..3
  const int wv  = threadIdx.x >> 6;          // wave 0..15
  const int ln  = threadIdx.x & 63;

  const int n = blockIdx.x * VPB + vid;

  // ---- load this thread's x row into registers (64 floats) ----
  const float4* xp = (const float4*)(x + (size_t)n * D);
  float4 xv[16];
#pragma unroll
  for (int i = 0; i < 16; ++i) xv[i] = xp[i];

  // ---- staging: chunk c (CK codewords = 32 KB, contiguous in w) into parity p
  auto stage = [&](int c, int p) {
    const char* gb = (const char*)w + (size_t)c * CK * D * 4;
#pragma unroll
    for (int j = 0; j < 2; ++j) {          // 16 waves x 2 KB = 32 KB
      unsigned off = wv * 2048 + j * 1024; // wave-uniform LDS offset
      gbl_void_t* gp = (gbl_void_t*)(gb + off + ln * 16);
      lds_void_t* lp = (lds_void_t*)((char*)&s_w[p][0] + off);
      __builtin_amdgcn_global_load_lds(gp, lp, 16, 0, 0);
    }
    if (wv == 0 && ln < CK / 4) {          // 32 lanes x 16 B = 512 B
      gbl_void_t* gp = (gbl_void_t*)((const char*)(hq + c * CK) + ln * 16);
      lds_void_t* lp = (lds_void_t*)&s_h[p][0];
      __builtin_amdgcn_global_load_lds(gp, lp, 16, 0, 0);
    }
  };

  float best = -1e30f;
  int bidx = 0;

  stage(0, 0);
  asm volatile("s_waitcnt vmcnt(0)" ::: "memory");
  __syncthreads();

  for (int c = 0; c < NCHUNK; ++c) {
    const int p = c & 1;
    if (c + 1 < NCHUNK) stage(c + 1, p ^ 1);   // prefetch next chunk

    // compute on staged chunk: this group's CKG codewords
#pragma unroll 2
    for (int kk = 0; kk < CKG; ++kk) {
      const int kl = grp * CKG + kk;                       // index within chunk
      const float4* wr = (const float4*)&s_w[p][kl * D];   // wave-uniform -> broadcast
      const float hw = s_h[p][kl];
      float ax = -hw, ay = 0.f, az = 0.f, aw = 0.f;
#pragma unroll
      for (int i = 0; i < 16; ++i) {
        float4 wv4 = wr[i];
        ax = fmaf(xv[i].x, wv4.x, ax);
        ay = fmaf(xv[i].y, wv4.y, ay);
        az = fmaf(xv[i].z, wv4.z, az);
        aw = fmaf(xv[i].w, wv4.w, aw);
      }
      const float m = (ax + ay) + (az + aw);
      const int kg = c * CK + kl;                          // global codeword idx
      if (m > best) { best = m; bidx = kg; }               // within-group: ascending k
    }

    asm volatile("s_waitcnt vmcnt(0)" ::: "memory");
    __syncthreads();
  }

  // ---- merge the 4 k-groups (exact first-index tie-break) ----
  s_ms[grp * VPB + vid] = best;
  s_mi[grp * VPB + vid] = bidx;
  __syncthreads();

  if (grp == 0) {
    float b = s_ms[vid];
    int bi = s_mi[vid];
#pragma unroll
    for (int g = 1; g < GROUPS; ++g) {
      float v = s_ms[g * VPB + vid];
      int vi = s_mi[g * VPB + vid];
      if (v > b || (v == b && vi < bi)) { b = v; bi = vi; }
    }

    // epilogue: gather codeword, write quantized + idx, accumulate loss
    const float4* qr = (const float4*)(w + (size_t)bi * D);
    float4* oq = (float4*)(out + OFF_Q + (size_t)n * D);
    float sse = 0.f;
#pragma unroll
    for (int i = 0; i < 16; ++i) {
      float4 q = qr[i];
      oq[i] = q;
      float d0 = xv[i].x - q.x, d1 = xv[i].y - q.y;
      float d2 = xv[i].z - q.z, d3 = xv[i].w - q.w;
      sse += d0 * d0 + d1 * d1 + d2 * d2 + d3 * d3;
    }
    out[OFF_IDX + n] = (float)bi;

#pragma unroll
    for (int off = 32; off >= 1; off >>= 1)
      sse += __shfl_xor(sse, off, 64);
    if (ln == 0)
      atomicAdd(out + OFF_LOSS, sse * (BETA / (float)(N_VEC * D)));
  }
}

extern "C" void kernel_launch(void* const* d_in, const int* in_sizes, int n_in,
                              void* d_out, int out_size, void* d_ws, size_t ws_size,
                              hipStream_t stream) {
  const float* x = (const float*)d_in[0];
  const float* w = (const float*)d_in[1];
  float* out = (float*)d_out;
  float* halfwsq = (float*)d_ws;   // 1024 floats of scratch

  hipMemsetAsync(out + OFF_LOSS, 0, sizeof(float), stream);
  vq_prep<<<256, 256, 0, stream>>>(w, halfwsq, out + OFF_WT);
  vq_main<<<N_VEC / VPB, TPB, 0, stream>>>(x, w, halfwsq, out);
}

// Round 3
// 130.194 us; speedup vs baseline: 3.8134x; 2.2084x over previous
//
#include <hip/hip_runtime.h>

// VQ-VAE VectorQuantizer forward, MI355X (gfx950) — MFMA fp16-split version
// inputs: d_in[0] = x (65536 x 64 f32), d_in[1] = w (1024 x 64 f32)
// out (f32 flat): [0..4194304) quantized, [4194304] loss,
//                 [4194305..+65536) indices (as float), [4259841..+65536) w.T

#define N_VEC 65536
#define D 64
#define K 1024
#define BETA 0.25f

#define OFF_Q    0
#define OFF_LOSS 4194304
#define OFF_IDX  4194305
#define OFF_WT   4259841

// ws layout (bytes): frag-ordered fp16 codebook + (-0.5*||w||^2)
#define WS_WHI  0         // 128 KB
#define WS_WLO  131072    // 128 KB
#define WS_HNEG 262144    // 4 KB

typedef _Float16 v8h __attribute__((ext_vector_type(8)));
typedef float v16f __attribute__((ext_vector_type(16)));
typedef __attribute__((address_space(3))) void lds_void_t;
typedef __attribute__((address_space(1))) const void gbl_void_t;

// ---------------- prep: w^T out, frag-ordered fp16 hi/lo codebook, -0.5||w||^2
// frag order: elem e = ((t*4 + ks)*64 + l)*8 + j  ->  w[t*32 + (l&31)][ks*16 + (l>>5)*8 + j]
// so a wave's B-frag read (lane l reads 16 B at base + l*16) is fully contiguous.
__global__ __launch_bounds__(256) void vq_prep(const float* __restrict__ w,
                                               char* __restrict__ ws,
                                               float* __restrict__ out_wt) {
  int tid = blockIdx.x * 256 + threadIdx.x;  // 0..65535
  { // w^T (coalesced write): wt[d*1024 + k] = w[k*64 + d]
    int k = tid & 1023, d = tid >> 10;
    out_wt[tid] = w[k * 64 + d];
  }
  { // fragment-ordered fp16 hi/lo
    int j = tid & 7, l = (tid >> 3) & 63, ks = (tid >> 9) & 3, t = tid >> 11;
    int code = (t << 5) | (l & 31);
    int depth = ks * 16 + ((l >> 5) << 3) + j;
    float v = w[code * 64 + depth];
    _Float16 hi = (_Float16)v;
    _Float16 lo = (_Float16)(v - (float)hi);
    ((_Float16*)(ws + WS_WHI))[tid] = hi;
    ((_Float16*)(ws + WS_WLO))[tid] = lo;
  }
  if (tid < K) {
    const float4* wr = (const float4*)(w + (size_t)tid * D);
    float s = 0.f;
#pragma unroll
    for (int i = 0; i < 16; ++i) {
      float4 v = wr[i];
      s += v.x * v.x + v.y * v.y + v.z * v.z + v.w * v.w;
    }
    ((float*)(ws + WS_HNEG))[tid] = -0.5f * s;
  }
}

// ---------------- main: 512 blocks x 256 thr (4 waves x 32 rows = 128 rows/block)
// chunk = 64 codes (2 ctiles), double-buffered; 16 chunks scan all 1024 codes.
// LDS: [0,32768) w dbuf (2 x 16 KB: 8 KB hi + 8 KB lo)  [reused as x-scratch in epilogue]
//      [32768,36864) hneg (1024 f32), [36864,37376) res idx (128 int)
#define TPB 256
#define ROWS_PB 128
#define NCH 16

__global__ __launch_bounds__(256) void vq_main(const float* __restrict__ x,
                                               const float* __restrict__ w,
                                               const char* __restrict__ ws,
                                               float* __restrict__ out) {
  __shared__ __align__(16) char lds[37376];
  const int tid = threadIdx.x;
  const int wv = tid >> 6, ln = tid & 63;
  const int col = ln & 31, hi = ln >> 5;
  const int rowBlk = blockIdx.x * ROWS_PB;
  const int myRow = rowBlk + wv * 32 + col;   // x-row whose A-frag this lane holds

  // ---- A fragments: x row -> fp16 hi/lo, 4 ksteps x 8 elems (k = hi*8 + j + 16*ks)
  v8h ah[4], al[4];
  {
    const float* xr = x + (size_t)myRow * D + hi * 8;
#pragma unroll
    for (int ks = 0; ks < 4; ++ks) {
      float4 v0 = *(const float4*)(xr + ks * 16);
      float4 v1 = *(const float4*)(xr + ks * 16 + 4);
      float xe[8] = {v0.x, v0.y, v0.z, v0.w, v1.x, v1.y, v1.z, v1.w};
#pragma unroll
      for (int j = 0; j < 8; ++j) {
        _Float16 h = (_Float16)xe[j];
        ah[ks][j] = h;
        al[ks][j] = (_Float16)(xe[j] - (float)h);
      }
    }
  }

  // ---- staging: chunk c (64 codes: 8 KB hi + 8 KB lo) into parity p
  auto stage = [&](int c, int p) {
    const char* ghi = ws + WS_WHI + c * 8192;
    const char* glo = ws + WS_WLO + c * 8192;
#pragma unroll
    for (int j = 0; j < 2; ++j) {
      unsigned off = j * 4096 + tid * 16;   // wave-uniform base + lane*16
      __builtin_amdgcn_global_load_lds((gbl_void_t*)(ghi + off),
                                       (lds_void_t*)(lds + p * 16384 + off), 16, 0, 0);
      __builtin_amdgcn_global_load_lds((gbl_void_t*)(glo + off),
                                       (lds_void_t*)(lds + p * 16384 + 8192 + off), 16, 0, 0);
    }
  };

  v16f best;
  int bidx[16];
#pragma unroll
  for (int r = 0; r < 16; ++r) { best[r] = -3.0e38f; bidx[r] = 0; }

  // prologue: stage chunk 0 + hneg
  stage(0, 0);
  __builtin_amdgcn_global_load_lds((gbl_void_t*)(ws + WS_HNEG + tid * 16),
                                   (lds_void_t*)(lds + 32768 + tid * 16), 16, 0, 0);
  asm volatile("s_waitcnt vmcnt(0)" ::: "memory");
  __syncthreads();

  const float* hn_l = (const float*)(lds + 32768);

  for (int c = 0; c < NCH; ++c) {
    const int p = c & 1;
    if (c + 1 < NCH) stage(c + 1, p ^ 1);
    const char* wb = lds + p * 16384;

    // two ctiles (64 codes) -> two independent accumulator chains
    const float h0 = hn_l[c * 64 + col];
    const float h1 = hn_l[c * 64 + 32 + col];
    v16f aA, aB;
#pragma unroll
    for (int r = 0; r < 16; ++r) { aA[r] = h0; aB[r] = h1; }

#pragma unroll
    for (int ks = 0; ks < 4; ++ks) {
      v8h bhA = *(const v8h*)(wb + ks * 1024 + ln * 16);
      v8h blA = *(const v8h*)(wb + 8192 + ks * 1024 + ln * 16);
      v8h bhB = *(const v8h*)(wb + 4096 + ks * 1024 + ln * 16);
      v8h blB = *(const v8h*)(wb + 8192 + 4096 + ks * 1024 + ln * 16);
      aA = __builtin_amdgcn_mfma_f32_32x32x16_f16(ah[ks], bhA, aA, 0, 0, 0);
      aB = __builtin_amdgcn_mfma_f32_32x32x16_f16(ah[ks], bhB, aB, 0, 0, 0);
      aA = __builtin_amdgcn_mfma_f32_32x32x16_f16(al[ks], bhA, aA, 0, 0, 0);
      aB = __builtin_amdgcn_mfma_f32_32x32x16_f16(al[ks], bhB, aB, 0, 0, 0);
      aA = __builtin_amdgcn_mfma_f32_32x32x16_f16(ah[ks], blA, aA, 0, 0, 0);
      aB = __builtin_amdgcn_mfma_f32_32x32x16_f16(ah[ks], blB, aB, 0, 0, 0);
    }

    const int kgA = c * 64 + col;       // ascending order => strict > keeps first max
    const int kgB = c * 64 + 32 + col;
#pragma unroll
    for (int r = 0; r < 16; ++r) {
      if (aA[r] > best[r]) { best[r] = aA[r]; bidx[r] = kgA; }
      if (aB[r] > best[r]) { best[r] = aB[r]; bidx[r] = kgB; }
    }

    asm volatile("s_waitcnt vmcnt(0)" ::: "memory");
    __syncthreads();
  }

  // ---- cross-lane argmax reduce over the 32 codeword-cols (xor masks stay in half)
#pragma unroll
  for (int m = 1; m <= 16; m <<= 1) {
#pragma unroll
    for (int r = 0; r < 16; ++r) {
      float ov = __shfl_xor(best[r], m, 64);
      int oi = __shfl_xor(bidx[r], m, 64);
      if (ov > best[r] || (ov == best[r] && oi < bidx[r])) { best[r] = ov; bidx[r] = oi; }
    }
  }

  // ---- publish per-row winners; reconstruct x into LDS (swizzled) for the loss
  int* res = (int*)(lds + 36864);
  if (col == 0) {
#pragma unroll
    for (int r = 0; r < 16; ++r) {
      int row = (r & 3) + 8 * (r >> 2) + 4 * hi;   // C/D row mapping
      res[wv * 32 + row] = bidx[r];
    }
  }
  {
    const int row = wv * 32 + col;
    const unsigned swz = (unsigned)((row & 7) << 4);
#pragma unroll
    for (int ks = 0; ks < 4; ++ks) {
      float4 q0 = make_float4((float)ah[ks][0] + (float)al[ks][0],
                              (float)ah[ks][1] + (float)al[ks][1],
                              (float)ah[ks][2] + (float)al[ks][2],
                              (float)ah[ks][3] + (float)al[ks][3]);
      float4 q1 = make_float4((float)ah[ks][4] + (float)al[ks][4],
                              (float)ah[ks][5] + (float)al[ks][5],
                              (float)ah[ks][6] + (float)al[ks][6],
                              (float)ah[ks][7] + (float)al[ks][7]);
      unsigned b = (unsigned)(row * 256 + (ks * 16 + hi * 8) * 4);
      *(float4*)((char*)lds + (b ^ swz)) = q0;
      *(float4*)((char*)lds + ((b + 16) ^ swz)) = q1;
    }
  }
  __syncthreads();

  // ---- epilogue: 2 lanes per row; gather w[bidx], write quantized + idx, loss
  const int erow = ln >> 1;
  const int half = ln & 1;
  const int growLocal = wv * 32 + erow;
  const int grow = rowBlk + growLocal;
  const int bi = res[growLocal];
  if (half == 0) out[OFF_IDX + grow] = (float)bi;

  const float4* qsrc = (const float4*)(w + (size_t)bi * D + half * 32);
  float4* qdst = (float4*)(out + OFF_Q + (size_t)grow * D + half * 32);
  const unsigned eswz = (unsigned)((growLocal & 7) << 4);
  float sse = 0.f;
#pragma unroll
  for (int i = 0; i < 8; ++i) {
    float4 q = qsrc[i];
    qdst[i] = q;
    unsigned b = (unsigned)(growLocal * 256 + half * 128 + i * 16);
    float4 xv4 = *(const float4*)((const char*)lds + (b ^ eswz));
    float d0 = q.x - xv4.x, d1 = q.y - xv4.y;
    float d2 = q.z - xv4.z, d3 = q.w - xv4.w;
    sse += d0 * d0 + d1 * d1 + d2 * d2 + d3 * d3;
  }
#pragma unroll
  for (int off = 32; off >= 1; off >>= 1) sse += __shfl_xor(sse, off, 64);
  if (ln == 0) atomicAdd(out + OFF_LOSS, sse * (BETA / (float)(N_VEC * D)));
}

extern "C" void kernel_launch(void* const* d_in, const int* in_sizes, int n_in,
                              void* d_out, int out_size, void* d_ws, size_t ws_size,
                              hipStream_t stream) {
  const float* x = (const float*)d_in[0];
  const float* w = (const float*)d_in[1];
  float* out = (float*)d_out;
  char* ws = (char*)d_ws;

  hipMemsetAsync(out + OFF_LOSS, 0, sizeof(float), stream);
  vq_prep<<<256, 256, 0, stream>>>(w, ws, out + OFF_WT);
  vq_main<<<N_VEC / ROWS_PB, TPB, 0, stream>>>(x, w, ws, out);
}